// Round 6
// baseline (219.410 us; speedup 1.0000x reference)
//
#include <hip/hip_runtime.h>

typedef __attribute__((ext_vector_type(8))) short bf16x8;
typedef __attribute__((ext_vector_type(4))) float f32x4;

__device__ __forceinline__ unsigned short f2bf(float f) {
  unsigned int u = __builtin_bit_cast(unsigned int, f);
  unsigned int r = (u + 0x7FFFu + ((u >> 16) & 1u)) >> 16;  // RNE (finite inputs)
  return (unsigned short)r;
}

// Build bf16 transposed + 16B-chunk-XOR-swizzled weight images in ws.
// wm_img[i]: [col(64)][k(64)] bf16, 128B rows, chunk ^= (col&7); val = Wm[i][k][col]
//            k 0..31 = W_self, k 32..63 = W_nb
// wu_img:    [col(64)][k(128, pad)] bf16, 256B rows, chunk ^= (col&7); k<96: Wu[k][col]
__global__ void prep_weights(const float* __restrict__ Wm,
                             const float* __restrict__ Wu,
                             unsigned short* __restrict__ wm_img,
                             unsigned short* __restrict__ wu_img) {
  const int i = blockIdx.x;
  const int tid = threadIdx.x;
  if (i < 26) {
    for (int e = tid; e < 4096; e += 256) {
      const int col = e & 63, k = e >> 6;
      const float v = Wm[(i * 64 + k) * 64 + col];
      const int bo = col * 128 + (((k >> 3) ^ (col & 7)) << 4) + (k & 7) * 2;
      wm_img[i * 4096 + (bo >> 1)] = f2bf(v);
    }
  } else {
    for (int e = tid; e < 8192; e += 256) {
      const int col = e >> 7, k = e & 127;
      const float v = (k < 96) ? Wu[k * 64 + col] : 0.0f;
      const int bo = col * 256 + (((k >> 3) ^ (col & 7)) << 4) + (k & 7) * 2;
      wu_img[bo >> 1] = f2bf(v);
    }
  }
}

// Tile: 4x4x16 voxels. 512 threads = 8 waves; wave w owns TWO (tx,ty) columns
// of 16 z-voxels (gg=0,1) so each 8KB Wm-image pass feeds 2x the MFMA work:
// LDS was the saturated pipe in R5 (10 b128/wave-iter for 16 voxels ~= 593K
// cyc/CU ~= whole kernel). Now ~13 b128/wave-iter for 32 voxels (~336K).
//
// Occupancy model (R1-R5): unified VGPR+AGPR file, total budget = 512/waves
// per EU; (512,4) caps total at 128. R5 proved no-spill at 1 column; here the
// register diet vs R1 is: B-frags per-tt (live 8 not 32), epilogue Wu frags
// per-tt (live 12 not 48), bm via prefetched global regs (not LDS, not
// stalled). LDS 60768B <= 64KB -> 2 blocks/CU (pool is 128KB: R2 vs R3).
#define CB_STRIDE 10384  // 6*6*18*16 + 16B skew: staging lanes cb=0..3 distinct banks
__global__ __launch_bounds__(512, 4)
void voxconv_main(const float* __restrict__ x,
                  const float* __restrict__ occ,
                  const float* __restrict__ bm,
                  const float* __restrict__ bu,
                  const unsigned short* __restrict__ wm_img,
                  const unsigned short* __restrict__ wu_img,
                  float* __restrict__ out) {
  // x halo: [cb(4)][hx(6)][hy(6)][hz(18)][8ch] bf16 ; strides B: cb CB_STRIDE, hx 1728, hy 288, hz 16
  __shared__ __align__(16) unsigned short x_lds[2 * CB_STRIDE];  // 41536 B
  __shared__ __align__(16) float occ_lds[648];                   // [6][6][18] f32, 2592 B
  __shared__ __align__(16) unsigned short wm_buf[8192];          // 2 x 8KB dbuf; later agg scratch
  __shared__ __align__(16) float bu_lds[64];                     // 256 B
  // total 60768 B -> LDS_Block_Size 60928 -> 2 blocks/CU

  const int tid  = (int)threadIdx.x;
  const int lane = tid & 63;
  const int w    = tid >> 6;
  const int q    = lane >> 4;   // k-chunk / quarter-wave
  const int m    = lane & 15;   // A row (z) / C col (within 16)
  const int l7   = lane & 7;

  const int id = (int)blockIdx.x;
  const int b  = id >> 10;
  const int ix = (id >> 6) & 15;
  const int iy = (id >> 2) & 15;
  const int iz = id & 3;
  const int x0 = ix << 2, y0 = iy << 2, z0 = iz << 4;

  // ---- stage x halo (648 voxels x 4 ch-chunks = 2592 items), f32 -> bf16 ----
  for (int it = 0; it < 6; ++it) {
    const int t = tid + it * 512;
    if (t < 2592) {
      const int cb = t & 3;
      const int v  = t >> 2;
      const int hz = v % 18;
      const int v2 = v / 18;
      const int hy = v2 % 6;
      const int hx = v2 / 6;
      const int X = (x0 + 63 + hx) & 63;
      const int Y = (y0 + 63 + hy) & 63;
      const int Z = (z0 + 63 + hz) & 63;
      const int vox = ((b * 64 + X) * 64 + Y) * 64 + Z;
      const float4* s4 = (const float4*)(x + vox * 32 + cb * 8);
      const float4 f0 = s4[0];
      const float4 f1 = s4[1];
      uint4 P;
      P.x = (unsigned)f2bf(f0.x) | ((unsigned)f2bf(f0.y) << 16);
      P.y = (unsigned)f2bf(f0.z) | ((unsigned)f2bf(f0.w) << 16);
      P.z = (unsigned)f2bf(f1.x) | ((unsigned)f2bf(f1.y) << 16);
      P.w = (unsigned)f2bf(f1.z) | ((unsigned)f2bf(f1.w) << 16);
      *(uint4*)((char*)x_lds + cb * CB_STRIDE + hx * 1728 + hy * 288 + hz * 16) = P;
    }
  }
  // ---- stage occ halo (f32) ----
  for (int t = tid; t < 648; t += 512) {
    const int hz = t % 18;
    const int v2 = t / 18;
    const int hy = v2 % 6;
    const int hx = v2 / 6;
    const int X = (x0 + 63 + hx) & 63;
    const int Y = (y0 + 63 + hy) & 63;
    const int Z = (z0 + 63 + hz) & 63;
    occ_lds[t] = occ[((b * 64 + X) * 64 + Y) * 64 + Z];
  }
  // ---- stage bu + first Wm image ----
  if (tid < 64) bu_lds[tid] = bu[tid];
  ((uint4*)wm_buf)[tid] = ((const uint4*)wm_img)[tid];
  __syncthreads();

  // ---- per-thread constant addresses (wave w owns columns g = 2w, 2w+1) ----
  int aSelf[2], occSelf[2], voxBase[2];
  #pragma unroll
  for (int gg = 0; gg < 2; ++gg) {
    const int g  = w * 2 + gg;
    const int tx = g >> 2, ty = g & 3;
    aSelf[gg]   = q * CB_STRIDE + (tx + 1) * 1728 + (ty + 1) * 288 + (1 + m) * 16;
    occSelf[gg] = (tx + 1) * 108 + (ty + 1) * 18 + 1 + q * 4;
    voxBase[gg] = ((b * 64 + (x0 + tx)) * 64 + (y0 + ty)) * 64 + z0;
  }
  int bOffS[4], bOffN[4], colIdx[4];
  #pragma unroll
  for (int tt = 0; tt < 4; ++tt) {
    const int col = tt * 16 + m;
    colIdx[tt] = col;
    bOffS[tt] = col * 128 + ((q ^ l7) << 4);          // k chunk q   (self, k 0..31)
    bOffN[tt] = col * 128 + (((4 + q) ^ l7) << 4);    // k chunk 4+q (nb,  k 32..63)
  }

  float agg[2][4][4];
  float den[2][4];
  #pragma unroll
  for (int gg = 0; gg < 2; ++gg)
    #pragma unroll
    for (int j = 0; j < 4; ++j) {
      den[gg][j] = 0.0f;
      #pragma unroll
      for (int tt = 0; tt < 4; ++tt) agg[gg][tt][j] = 0.0f;
    }

  // bm row i=0 prefetched (6.6KB L2-resident table, 4 coalesced dwords/lane)
  float bmv[4];
  #pragma unroll
  for (int tt = 0; tt < 4; ++tt) bmv[tt] = bm[colIdx[tt]];

  // ---- 26-offset main loop, Wm double-buffered ----
  int cur = 0;
  #pragma unroll 1
  for (int i = 0; i < 26; ++i) {
    uint4 wnext;
    float bmn[4];
    if (i < 25) {
      wnext = ((const uint4*)(wm_img + (i + 1) * 4096))[tid];
      #pragma unroll
      for (int tt = 0; tt < 4; ++tt) bmn[tt] = bm[(i + 1) * 64 + colIdx[tt]];
    }

    const int oi  = (i < 13) ? i : i + 1;          // skip (0,0,0)
    const int dxo = oi / 9 - 1;
    const int dyo = (oi / 3) % 3 - 1;
    const int dzo = oi % 3 - 1;
    // neighbor q = p - d  (roll semantics: x_nb[p] = x[p-d])
    const int dA = -(dxo * 1728 + dyo * 288 + dzo * 16);
    const int dO = -(dxo * 108 + dyo * 18 + dzo);

    // A-frags + occ for both columns (shared across all tt)
    bf16x8 aS[2], aN[2];
    float on[2][4];
    #pragma unroll
    for (int gg = 0; gg < 2; ++gg) {
      aS[gg] = *(const bf16x8*)((const char*)x_lds + aSelf[gg]);
      aN[gg] = *(const bf16x8*)((const char*)x_lds + aSelf[gg] + dA);
      #pragma unroll
      for (int j = 0; j < 4; ++j) on[gg][j] = occ_lds[occSelf[gg] + dO + j];
    }

    const char* wmc = (const char*)wm_buf + cur * 8192;
    // B-frags loaded per-tt (live 8 regs, shared by both columns' MFMAs)
    #pragma unroll
    for (int tt = 0; tt < 4; ++tt) {
      const bf16x8 bS = *(const bf16x8*)(wmc + bOffS[tt]);
      const bf16x8 bN = *(const bf16x8*)(wmc + bOffN[tt]);
      #pragma unroll
      for (int gg = 0; gg < 2; ++gg) {
        f32x4 acc = {bmv[tt], bmv[tt], bmv[tt], bmv[tt]};
        acc = __builtin_amdgcn_mfma_f32_16x16x32_bf16(aS[gg], bS, acc, 0, 0, 0);
        acc = __builtin_amdgcn_mfma_f32_16x16x32_bf16(aN[gg], bN, acc, 0, 0, 0);
        #pragma unroll
        for (int j = 0; j < 4; ++j) {
          const float msg = fmaxf(acc[j], 0.0f);
          agg[gg][tt][j] = fmaf(msg, on[gg][j], agg[gg][tt][j]);
        }
      }
    }
    #pragma unroll
    for (int gg = 0; gg < 2; ++gg)
      #pragma unroll
      for (int j = 0; j < 4; ++j) den[gg][j] += on[gg][j];

    if (i < 25) {
      *(uint4*)((char*)wm_buf + (cur ^ 1) * 8192 + tid * 16) = wnext;
      #pragma unroll
      for (int tt = 0; tt < 4; ++tt) bmv[tt] = bmn[tt];
    }
    __syncthreads();
    cur ^= 1;
  }

  // ---- agg /= (den + 1e-8) ----
  #pragma unroll
  for (int gg = 0; gg < 2; ++gg)
    #pragma unroll
    for (int j = 0; j < 4; ++j) {
      const float r = 1.0f / (den[gg][j] + 1e-8f);
      #pragma unroll
      for (int tt = 0; tt < 4; ++tt) agg[gg][tt][j] *= r;
    }

  // ---- update matmul: out = ([x|agg] @ Wu + bu) * occ_self ----
  char* scratch = (char*)wm_buf + w * 2048;  // per-wave 16 rows x 128B (aliases dbuf; private per wave)
  float buv[4];
  #pragma unroll
  for (int tt = 0; tt < 4; ++tt) buv[tt] = bu_lds[colIdx[tt]];

  #pragma unroll
  for (int gg = 0; gg < 2; ++gg) {
    // C-layout agg -> bf16 A-layout scratch (row-XOR swizzle); per-wave private,
    // wave-synchronous: no barrier needed (DS ops complete in order per wave)
    #pragma unroll
    for (int tt = 0; tt < 4; ++tt) {
      const int colhi = tt * 2 + ((lane >> 3) & 1);  // col>>3
      #pragma unroll
      for (int j = 0; j < 4; ++j) {
        const int row = q * 4 + j;
        const int bo = row * 128 + ((colhi ^ (row & 7)) << 4) + l7 * 2;
        *(unsigned short*)(scratch + bo) = f2bf(agg[gg][tt][j]);
      }
    }
    const bf16x8 ax  = *(const bf16x8*)((const char*)x_lds + aSelf[gg]);
    const bf16x8 ag0 = *(const bf16x8*)(scratch + m * 128 + ((q ^ (m & 7)) << 4));
    const bf16x8 ag1 = *(const bf16x8*)(scratch + m * 128 + (((4 + q) ^ (m & 7)) << 4));
    float os[4];
    #pragma unroll
    for (int j = 0; j < 4; ++j) os[j] = occ_lds[occSelf[gg] + j];
    // Wu fragments per-tt from global (L2-resident 16KB image) to cap live regs
    #pragma unroll
    for (int tt = 0; tt < 4; ++tt) {
      const char* wc = (const char*)wu_img + colIdx[tt] * 256;
      const bf16x8 bux  = *(const bf16x8*)(wc + ((q ^ l7) << 4));        // Wu k 0..31 (x)
      const bf16x8 bua0 = *(const bf16x8*)(wc + (((4 + q) ^ l7) << 4));  // Wu k 32..63
      const bf16x8 bua1 = *(const bf16x8*)(wc + (((8 + q) ^ l7) << 4));  // Wu k 64..95
      f32x4 acc = {buv[tt], buv[tt], buv[tt], buv[tt]};
      acc = __builtin_amdgcn_mfma_f32_16x16x32_bf16(ax,  bux,  acc, 0, 0, 0);
      acc = __builtin_amdgcn_mfma_f32_16x16x32_bf16(ag0, bua0, acc, 0, 0, 0);
      acc = __builtin_amdgcn_mfma_f32_16x16x32_bf16(ag1, bua1, acc, 0, 0, 0);
      #pragma unroll
      for (int j = 0; j < 4; ++j) {
        out[(voxBase[gg] + q * 4 + j) * 64 + colIdx[tt]] = acc[j] * os[j];
      }
    }
  }
}

extern "C" void kernel_launch(void* const* d_in, const int* in_sizes, int n_in,
                              void* d_out, int out_size, void* d_ws, size_t ws_size,
                              hipStream_t stream) {
  const float* x   = (const float*)d_in[0];
  const float* occ = (const float*)d_in[1];
  const float* Wm  = (const float*)d_in[2];
  const float* bm  = (const float*)d_in[3];
  const float* Wu  = (const float*)d_in[4];
  const float* bu  = (const float*)d_in[5];
  float* out = (float*)d_out;

  unsigned short* wm_img = (unsigned short*)d_ws;        // 26*4096 ushort = 208 KB
  unsigned short* wu_img = wm_img + 26 * 4096;           // 8192 ushort   =  16 KB

  prep_weights<<<27, 256, 0, stream>>>(Wm, Wu, wm_img, wu_img);
  voxconv_main<<<2048, 512, 0, stream>>>(x, occ, bm, bu, wm_img, wu_img, out);
}

// Round 7
// 185.057 us; speedup vs baseline: 1.1856x; 1.1856x over previous
//
#include <hip/hip_runtime.h>

typedef __attribute__((ext_vector_type(8))) short bf16x8;
typedef __attribute__((ext_vector_type(4))) float f32x4;

__device__ __forceinline__ unsigned short f2bf(float f) {
  unsigned int u = __builtin_bit_cast(unsigned int, f);
  unsigned int r = (u + 0x7FFFu + ((u >> 16) & 1u)) >> 16;  // RNE (finite inputs)
  return (unsigned short)r;
}

// Build bf16 transposed + 16B-chunk-XOR-swizzled weight images in ws.
// wm_img[i]: [col(64)][k(64)] bf16, 128B rows, chunk ^= (col&7); val = Wm[i][k][col]
//            k 0..31 = W_self, k 32..63 = W_nb
// wu_img:    [col(64)][k(128, pad)] bf16, 256B rows, chunk ^= (col&7); k<96: Wu[k][col]
__global__ void prep_weights(const float* __restrict__ Wm,
                             const float* __restrict__ Wu,
                             unsigned short* __restrict__ wm_img,
                             unsigned short* __restrict__ wu_img) {
  const int i = blockIdx.x;
  const int tid = threadIdx.x;
  if (i < 26) {
    for (int e = tid; e < 4096; e += 256) {
      const int col = e & 63, k = e >> 6;
      const float v = Wm[(i * 64 + k) * 64 + col];
      const int bo = col * 128 + (((k >> 3) ^ (col & 7)) << 4) + (k & 7) * 2;
      wm_img[i * 4096 + (bo >> 1)] = f2bf(v);
    }
  } else {
    for (int e = tid; e < 8192; e += 256) {
      const int col = e >> 7, k = e & 127;
      const float v = (k < 96) ? Wu[k * 64 + col] : 0.0f;
      const int bo = col * 256 + (((k >> 3) ^ (col & 7)) << 4) + (k & 7) * 2;
      wu_img[bo >> 1] = f2bf(v);
    }
  }
}

// Tile: 4x4x16 voxels. 512 threads = 8 waves; wave w owns TWO (tx,ty) columns
// of 16 z-voxels (gg=0,1) so each 8KB Wm-image pass feeds 2x the MFMA work
// (LDS pipe was saturated at 1 column/wave, R5).
//
// Occupancy model (R1-R6): unified VGPR+AGPR file, total budget = 512 /
// (waves/EU); (512,4) caps total at 128. R6 spilled ~8 regs (WRITE_SIZE
// 131->165MB) from loop-carried prefetch state. Fix here: Wm prefetch via
// __builtin_amdgcn_global_load_lds (dbuf layout is already wave-uniform
// base + lane*16 -> no VGPR round-trip, no ds_write), bm loaded in-loop
// (L2-hot), aS hoisted (x_lds immutable). LDS 60.5KB -> 2 blocks/CU
// (pool is 128KB: R2 vs R3 evidence).
#define CB_STRIDE 10384  // 6*6*18*16 + 16B skew: staging lanes cb=0..3 distinct banks
__global__ __launch_bounds__(512, 4)
void voxconv_main(const float* __restrict__ x,
                  const float* __restrict__ occ,
                  const float* __restrict__ bm,
                  const float* __restrict__ bu,
                  const unsigned short* __restrict__ wm_img,
                  const unsigned short* __restrict__ wu_img,
                  float* __restrict__ out) {
  // x halo: [cb(4)][hx(6)][hy(6)][hz(18)][8ch] bf16 ; strides B: cb CB_STRIDE, hx 1728, hy 288, hz 16
  __shared__ __align__(16) unsigned short x_lds[2 * CB_STRIDE];  // 41536 B
  __shared__ __align__(16) float occ_lds[648];                   // [6][6][18] f32, 2592 B
  __shared__ __align__(16) unsigned short wm_buf[8192];          // 2 x 8KB dbuf; later agg scratch
  // total 60512 B -> 2 blocks/CU

  const int tid  = (int)threadIdx.x;
  const int lane = tid & 63;
  const int w    = tid >> 6;
  const int q    = lane >> 4;   // k-chunk / quarter-wave
  const int m    = lane & 15;   // A row (z) / C col (within 16)
  const int l7   = lane & 7;

  const int id = (int)blockIdx.x;
  const int b  = id >> 10;
  const int ix = (id >> 6) & 15;
  const int iy = (id >> 2) & 15;
  const int iz = id & 3;
  const int x0 = ix << 2, y0 = iy << 2, z0 = iz << 4;

  // ---- stage x halo (648 voxels x 4 ch-chunks = 2592 items), f32 -> bf16 ----
  for (int it = 0; it < 6; ++it) {
    const int t = tid + it * 512;
    if (t < 2592) {
      const int cb = t & 3;
      const int v  = t >> 2;
      const int hz = v % 18;
      const int v2 = v / 18;
      const int hy = v2 % 6;
      const int hx = v2 / 6;
      const int X = (x0 + 63 + hx) & 63;
      const int Y = (y0 + 63 + hy) & 63;
      const int Z = (z0 + 63 + hz) & 63;
      const int vox = ((b * 64 + X) * 64 + Y) * 64 + Z;
      const float4* s4 = (const float4*)(x + vox * 32 + cb * 8);
      const float4 f0 = s4[0];
      const float4 f1 = s4[1];
      uint4 P;
      P.x = (unsigned)f2bf(f0.x) | ((unsigned)f2bf(f0.y) << 16);
      P.y = (unsigned)f2bf(f0.z) | ((unsigned)f2bf(f0.w) << 16);
      P.z = (unsigned)f2bf(f1.x) | ((unsigned)f2bf(f1.y) << 16);
      P.w = (unsigned)f2bf(f1.z) | ((unsigned)f2bf(f1.w) << 16);
      *(uint4*)((char*)x_lds + cb * CB_STRIDE + hx * 1728 + hy * 288 + hz * 16) = P;
    }
  }
  // ---- stage occ halo (f32) ----
  for (int t = tid; t < 648; t += 512) {
    const int hz = t % 18;
    const int v2 = t / 18;
    const int hy = v2 % 6;
    const int hx = v2 / 6;
    const int X = (x0 + 63 + hx) & 63;
    const int Y = (y0 + 63 + hy) & 63;
    const int Z = (z0 + 63 + hz) & 63;
    occ_lds[t] = occ[((b * 64 + X) * 64 + Y) * 64 + Z];
  }
  // ---- stage first Wm image ----
  ((uint4*)wm_buf)[tid] = ((const uint4*)wm_img)[tid];
  __syncthreads();

  // ---- per-thread constant addresses (wave w owns columns g = 2w, 2w+1) ----
  int aSelf[2], occSelf[2], voxBase[2];
  #pragma unroll
  for (int gg = 0; gg < 2; ++gg) {
    const int g  = w * 2 + gg;
    const int tx = g >> 2, ty = g & 3;
    aSelf[gg]   = q * CB_STRIDE + (tx + 1) * 1728 + (ty + 1) * 288 + (1 + m) * 16;
    occSelf[gg] = (tx + 1) * 108 + (ty + 1) * 18 + 1 + q * 4;
    voxBase[gg] = ((b * 64 + (x0 + tx)) * 64 + (y0 + ty)) * 64 + z0;
  }
  int bOffS[4], bOffN[4], colIdx[4];
  #pragma unroll
  for (int tt = 0; tt < 4; ++tt) {
    const int col = tt * 16 + m;
    colIdx[tt] = col;
    bOffS[tt] = col * 128 + ((q ^ l7) << 4);          // k chunk q   (self, k 0..31)
    bOffN[tt] = col * 128 + (((4 + q) ^ l7) << 4);    // k chunk 4+q (nb,  k 32..63)
  }

  // Loop-invariant self A-fragments (x_lds is immutable after prologue);
  // also reused as the epilogue's x fragment.
  bf16x8 aS[2];
  #pragma unroll
  for (int gg = 0; gg < 2; ++gg)
    aS[gg] = *(const bf16x8*)((const char*)x_lds + aSelf[gg]);

  float agg[2][4][4];
  float den[2][4];
  #pragma unroll
  for (int gg = 0; gg < 2; ++gg)
    #pragma unroll
    for (int j = 0; j < 4; ++j) {
      den[gg][j] = 0.0f;
      #pragma unroll
      for (int tt = 0; tt < 4; ++tt) agg[gg][tt][j] = 0.0f;
    }

  // Per-wave async-prefetch addresses: wave w's 1KB slice of the 8KB image.
  // global src per lane: img + (w*64+lane)*16B ; LDS dst: base + w*1024 + lane*16.
  const unsigned short* gsrc_base = wm_img + 4096 + (unsigned)tid * 8;  // image i+1 at iter i=0

  // ---- 26-offset main loop, Wm double-buffered via global_load_lds ----
  int cur = 0;
  #pragma unroll 1
  for (int i = 0; i < 26; ++i) {
    if (i < 25) {
      // async global->LDS: 16B/lane, wave-uniform LDS base (w*1024 slice)
      __builtin_amdgcn_global_load_lds(
          (const __attribute__((address_space(1))) void*)(gsrc_base + (unsigned)i * 4096),
          (__attribute__((address_space(3))) void*)((char*)wm_buf + (cur ^ 1) * 8192 + w * 1024 + (lane * 16)),
          16, 0, 0);
    }

    // bm row i from global: 6.6KB L2-resident table, issued early, used at MFMA init
    float bmv[4];
    #pragma unroll
    for (int tt = 0; tt < 4; ++tt) bmv[tt] = bm[i * 64 + colIdx[tt]];

    const int oi  = (i < 13) ? i : i + 1;          // skip (0,0,0)
    const int dxo = oi / 9 - 1;
    const int dyo = (oi / 3) % 3 - 1;
    const int dzo = oi % 3 - 1;
    // neighbor q = p - d  (roll semantics: x_nb[p] = x[p-d])
    const int dA = -(dxo * 1728 + dyo * 288 + dzo * 16);
    const int dO = -(dxo * 108 + dyo * 18 + dzo);

    // neighbor A-frags + occ for both columns (shared across all tt)
    bf16x8 aN[2];
    float on[2][4];
    #pragma unroll
    for (int gg = 0; gg < 2; ++gg) {
      aN[gg] = *(const bf16x8*)((const char*)x_lds + aSelf[gg] + dA);
      #pragma unroll
      for (int j = 0; j < 4; ++j) on[gg][j] = occ_lds[occSelf[gg] + dO + j];
    }

    const char* wmc = (const char*)wm_buf + cur * 8192;
    // B-frags loaded per-tt (live 8 regs, shared by both columns' MFMAs)
    #pragma unroll
    for (int tt = 0; tt < 4; ++tt) {
      const bf16x8 bS = *(const bf16x8*)(wmc + bOffS[tt]);
      const bf16x8 bN = *(const bf16x8*)(wmc + bOffN[tt]);
      #pragma unroll
      for (int gg = 0; gg < 2; ++gg) {
        f32x4 acc = {bmv[tt], bmv[tt], bmv[tt], bmv[tt]};
        acc = __builtin_amdgcn_mfma_f32_16x16x32_bf16(aS[gg], bS, acc, 0, 0, 0);
        acc = __builtin_amdgcn_mfma_f32_16x16x32_bf16(aN[gg], bN, acc, 0, 0, 0);
        #pragma unroll
        for (int j = 0; j < 4; ++j) {
          const float msg = fmaxf(acc[j], 0.0f);
          agg[gg][tt][j] = fmaf(msg, on[gg][j], agg[gg][tt][j]);
        }
      }
    }
    #pragma unroll
    for (int gg = 0; gg < 2; ++gg)
      #pragma unroll
      for (int j = 0; j < 4; ++j) den[gg][j] += on[gg][j];

    // barrier drains vmcnt(0) -> prefetched image i+1 is resident in cur^1
    __syncthreads();
    cur ^= 1;
  }

  // ---- agg /= (den + 1e-8) ----
  #pragma unroll
  for (int gg = 0; gg < 2; ++gg)
    #pragma unroll
    for (int j = 0; j < 4; ++j) {
      const float r = 1.0f / (den[gg][j] + 1e-8f);
      #pragma unroll
      for (int tt = 0; tt < 4; ++tt) agg[gg][tt][j] *= r;
    }

  // ---- update matmul: out = ([x|agg] @ Wu + bu) * occ_self ----
  char* scratch = (char*)wm_buf + w * 2048;  // per-wave 16 rows x 128B (aliases dbuf; private per wave)
  float buv[4];
  #pragma unroll
  for (int tt = 0; tt < 4; ++tt) buv[tt] = bu[colIdx[tt]];

  #pragma unroll
  for (int gg = 0; gg < 2; ++gg) {
    // C-layout agg -> bf16 A-layout scratch (row-XOR swizzle); per-wave private,
    // wave-synchronous: no barrier needed (DS ops complete in order per wave)
    #pragma unroll
    for (int tt = 0; tt < 4; ++tt) {
      const int colhi = tt * 2 + ((lane >> 3) & 1);  // col>>3
      #pragma unroll
      for (int j = 0; j < 4; ++j) {
        const int row = q * 4 + j;
        const int bo = row * 128 + ((colhi ^ (row & 7)) << 4) + l7 * 2;
        *(unsigned short*)(scratch + bo) = f2bf(agg[gg][tt][j]);
      }
    }
    const bf16x8 ag0 = *(const bf16x8*)(scratch + m * 128 + ((q ^ (m & 7)) << 4));
    const bf16x8 ag1 = *(const bf16x8*)(scratch + m * 128 + (((4 + q) ^ (m & 7)) << 4));
    float os[4];
    #pragma unroll
    for (int j = 0; j < 4; ++j) os[j] = occ_lds[occSelf[gg] + j];
    // Wu fragments per-tt from global (L2-resident 16KB image) to cap live regs
    #pragma unroll
    for (int tt = 0; tt < 4; ++tt) {
      const char* wc = (const char*)wu_img + colIdx[tt] * 256;
      const bf16x8 bux  = *(const bf16x8*)(wc + ((q ^ l7) << 4));        // Wu k 0..31 (x)
      const bf16x8 bua0 = *(const bf16x8*)(wc + (((4 + q) ^ l7) << 4));  // Wu k 32..63
      const bf16x8 bua1 = *(const bf16x8*)(wc + (((8 + q) ^ l7) << 4));  // Wu k 64..95
      f32x4 acc = {buv[tt], buv[tt], buv[tt], buv[tt]};
      acc = __builtin_amdgcn_mfma_f32_16x16x32_bf16(aS[gg], bux,  acc, 0, 0, 0);
      acc = __builtin_amdgcn_mfma_f32_16x16x32_bf16(ag0,    bua0, acc, 0, 0, 0);
      acc = __builtin_amdgcn_mfma_f32_16x16x32_bf16(ag1,    bua1, acc, 0, 0, 0);
      #pragma unroll
      for (int j = 0; j < 4; ++j) {
        out[(voxBase[gg] + q * 4 + j) * 64 + colIdx[tt]] = acc[j] * os[j];
      }
    }
  }
}

extern "C" void kernel_launch(void* const* d_in, const int* in_sizes, int n_in,
                              void* d_out, int out_size, void* d_ws, size_t ws_size,
                              hipStream_t stream) {
  const float* x   = (const float*)d_in[0];
  const float* occ = (const float*)d_in[1];
  const float* Wm  = (const float*)d_in[2];
  const float* bm  = (const float*)d_in[3];
  const float* Wu  = (const float*)d_in[4];
  const float* bu  = (const float*)d_in[5];
  float* out = (float*)d_out;

  unsigned short* wm_img = (unsigned short*)d_ws;        // 26*4096 ushort = 208 KB
  unsigned short* wu_img = wm_img + 26 * 4096;           // 8192 ushort   =  16 KB

  prep_weights<<<27, 256, 0, stream>>>(Wm, Wu, wm_img, wu_img);
  voxconv_main<<<2048, 512, 0, stream>>>(x, occ, bm, bu, wm_img, wu_img, out);
}